// Round 12
// baseline (214.884 us; speedup 1.0000x reference)
//
#include <hip/hip_runtime.h>
#include <hip/hip_bf16.h>

#define BB 4
#define TT 2048
#define DIM 512
#define NH 8
#define HD 64
#define NROW (BB*TT)   // 8192
#define BH (BB*NH)     // 32

typedef unsigned short u16;
typedef unsigned int u32;
typedef __attribute__((ext_vector_type(8))) short bf16x8;   // 8 bf16 = 4 VGPRs
typedef __attribute__((ext_vector_type(8))) unsigned short u16x8;
typedef __attribute__((ext_vector_type(4))) float f32x4;
typedef __attribute__((ext_vector_type(16))) float f32x16;
typedef __attribute__((ext_vector_type(4))) unsigned short u16x4;

static __device__ __forceinline__ float bf2f(u16 u) {
    return __uint_as_float(((u32)u) << 16);
}
static __device__ __forceinline__ u16 f2bf(float f) {
    u32 u = __float_as_uint(f);
    u32 r = (u + 0x7FFFu + ((u >> 16) & 1u)) >> 16;
    return (u16)r;
}
// packed f32x2 -> bf16x2 (v_cvt_pk_bf16_f32 on gfx950)
static __device__ __forceinline__ u32 cvtpk(float a, float b) {
    union { __hip_bfloat162 h2; u32 u; } cv;
    cv.h2 = __float22bfloat162_rn(make_float2(a, b));
    return cv.u;
}

// ---------------- prep: fused convert_x (blocks 0..255) + W transposes
__global__ __launch_bounds__(256) void prep_kernel(
    const float* __restrict__ x, u16* __restrict__ x16, u32* __restrict__ bmaxsq,
    const float* __restrict__ Wqkv, u16* __restrict__ Wtq,
    const float* __restrict__ Wproj, u16* __restrict__ Wtp)
{
    const int bid = blockIdx.x;
    const int tid = threadIdx.x;
    __shared__ u16 t[32][33];
    __shared__ float red[4];

    if (bid < 256) {
        const int row = bid * 32 + (tid >> 3);
        const int b = (bid * 32) >> 11;
        const float* xr = x   + (size_t)row * DIM + (tid & 7) * 64;
        u16*        xo  = x16 + (size_t)row * DIM + (tid & 7) * 64;
        float s = 0.0f;
        #pragma unroll
        for (int j = 0; j < 8; ++j) {
            float4 a = *(const float4*)(xr + j*8);
            float4 c = *(const float4*)(xr + j*8 + 4);
            s += a.x*a.x + a.y*a.y + a.z*a.z + a.w*a.w;
            s += c.x*c.x + c.y*c.y + c.z*c.z + c.w*c.w;
            u16x8 pk;
            pk[0]=f2bf(a.x); pk[1]=f2bf(a.y); pk[2]=f2bf(a.z); pk[3]=f2bf(a.w);
            pk[4]=f2bf(c.x); pk[5]=f2bf(c.y); pk[6]=f2bf(c.z); pk[7]=f2bf(c.w);
            *(u16x8*)(xo + j*8) = pk;
        }
        #pragma unroll
        for (int off = 1; off < 8; off <<= 1) s += __shfl_xor(s, off, 64);
        float m = s;
        #pragma unroll
        for (int off = 8; off < 64; off <<= 1) m = fmaxf(m, __shfl_xor(m, off, 64));
        if ((tid & 63) == 0) red[tid >> 6] = m;
        __syncthreads();
        if (tid == 0) {
            float mx = fmaxf(fmaxf(red[0], red[1]), fmaxf(red[2], red[3]));
            atomicMax(&bmaxsq[b], __float_as_uint(mx));
        }
    } else {
        const float* in; u16* outp; int K, N, tb;
        if (bid < 768) { in = Wqkv; outp = Wtq; K = 512; N = 1024; tb = bid - 256; }
        else           { in = Wproj; outp = Wtp; K = 512; N = 512;  tb = bid - 768; }
        const int ntiles = N >> 5;
        const int bx = tb % ntiles, by = tb / ntiles;
        const int n0 = bx * 32, k0 = by * 32;
        const int tx = tid & 31, ty = tid >> 5;
        #pragma unroll
        for (int i = 0; i < 32; i += 8)
            t[ty + i][tx] = f2bf(in[(size_t)(k0 + ty + i) * N + n0 + tx]);
        __syncthreads();
        #pragma unroll
        for (int i = 0; i < 32; i += 8)
            outp[(size_t)(n0 + ty + i) * K + k0 + tx] = t[tx][ty + i];
    }
}

// ---------------- MFMA GEMM: qkv = x16 @ Wqkv (via Wt [1024][512] bf16)
#define LDG 72
__global__ __launch_bounds__(256) void qkv_mfma(
    const u16* __restrict__ x16, const u16* __restrict__ Wt,
    u16* __restrict__ q16, u16* __restrict__ vt16)
{
    const int tid = threadIdx.x, lane = tid & 63, w = tid >> 6;
    const int li = lane & 15, quad = lane >> 4;
    const int mb = blockIdx.x >> 3, nb = blockIdx.x & 7;   // 64 x 8
    const int row0 = mb * 128, n0 = nb * 128;
    const int b = row0 >> 11;
    const int wm = w >> 1, wn = w & 1;

    __shared__ __align__(16) u16 as[128 * LDG];
    __shared__ __align__(16) u16 bs[128 * LDG];

    f32x4 acc[4][4];
    #pragma unroll
    for (int mi = 0; mi < 4; ++mi)
        #pragma unroll
        for (int ni = 0; ni < 4; ++ni) acc[mi][ni] = f32x4{0.f,0.f,0.f,0.f};

    for (int k0 = 0; k0 < DIM; k0 += 64) {
        __syncthreads();
        #pragma unroll
        for (int it = 0; it < 4; ++it) {
            int id = it * 256 + tid;
            int r = id >> 3, c = id & 7;
            *(bf16x8*)&as[r*LDG + c*8] =
                *(const bf16x8*)(x16 + (size_t)(row0 + r)*DIM + k0 + c*8);
            *(bf16x8*)&bs[r*LDG + c*8] =
                *(const bf16x8*)(Wt  + (size_t)(n0  + r)*DIM + k0 + c*8);
        }
        __syncthreads();

        bf16x8 af[4][2], bfr[4][2];
        #pragma unroll
        for (int mi = 0; mi < 4; ++mi) {
            const u16* p = &as[(wm*64 + mi*16 + li)*LDG + quad*8];
            af[mi][0] = *(const bf16x8*)p;
            af[mi][1] = *(const bf16x8*)(p + 32);
        }
        #pragma unroll
        for (int ni = 0; ni < 4; ++ni) {
            const u16* p = &bs[(wn*64 + ni*16 + li)*LDG + quad*8];
            bfr[ni][0] = *(const bf16x8*)p;
            bfr[ni][1] = *(const bf16x8*)(p + 32);
        }
        #pragma unroll
        for (int mi = 0; mi < 4; ++mi)
            #pragma unroll
            for (int ni = 0; ni < 4; ++ni) {
                acc[mi][ni] = __builtin_amdgcn_mfma_f32_16x16x32_bf16(
                    af[mi][0], bfr[ni][0], acc[mi][ni], 0, 0, 0);
                acc[mi][ni] = __builtin_amdgcn_mfma_f32_16x16x32_bf16(
                    af[mi][1], bfr[ni][1], acc[mi][ni], 0, 0, 0);
            }
    }

    const int h = li & 7;
    const bool isv = ((li >> 3) & 1) != 0;
    #pragma unroll
    for (int ni = 0; ni < 4; ++ni) {
        int col0 = n0 + wn*64 + ni*16;
        int d = col0 >> 4;
        #pragma unroll
        for (int mi = 0; mi < 4; ++mi) {
            int t0 = (row0 & (TT-1)) + wm*64 + mi*16 + quad*4;
            if (!isv) {
                u16* dst = q16 + ((size_t)(b*NH + h)*TT + t0)*HD + d;
                #pragma unroll
                for (int r = 0; r < 4; ++r)
                    dst[(size_t)r * HD] = f2bf(acc[mi][ni][r]);
            } else {
                u16x4 pk;
                pk.x = f2bf(acc[mi][ni][0]); pk.y = f2bf(acc[mi][ni][1]);
                pk.z = f2bf(acc[mi][ni][2]); pk.w = f2bf(acc[mi][ni][3]);
                *(u16x4*)(vt16 + ((size_t)(b*NH + h)*HD + d)*TT + t0) = pk;
            }
        }
    }
}

// ---------------- MFMA GEMM: out(f32) = ao16 @ Wproj + bias(f32)
__global__ __launch_bounds__(256) void proj_mfma(
    const u16* __restrict__ ao16, const u16* __restrict__ Wt,
    const float* __restrict__ bp, float* __restrict__ out)
{
    const int tid = threadIdx.x, lane = tid & 63, w = tid >> 6;
    const int li = lane & 15, quad = lane >> 4;
    const int mb = blockIdx.x >> 2, nb = blockIdx.x & 3;   // 64 x 4
    const int row0 = mb * 128, n0 = nb * 128;
    const int wm = w >> 1, wn = w & 1;

    __shared__ __align__(16) u16 as[128 * LDG];
    __shared__ __align__(16) u16 bs[128 * LDG];

    f32x4 acc[4][4];
    #pragma unroll
    for (int mi = 0; mi < 4; ++mi)
        #pragma unroll
        for (int ni = 0; ni < 4; ++ni) acc[mi][ni] = f32x4{0.f,0.f,0.f,0.f};

    for (int k0 = 0; k0 < DIM; k0 += 64) {
        __syncthreads();
        #pragma unroll
        for (int it = 0; it < 4; ++it) {
            int id = it * 256 + tid;
            int r = id >> 3, c = id & 7;
            *(bf16x8*)&as[r*LDG + c*8] =
                *(const bf16x8*)(ao16 + (size_t)(row0 + r)*DIM + k0 + c*8);
            *(bf16x8*)&bs[r*LDG + c*8] =
                *(const bf16x8*)(Wt   + (size_t)(n0  + r)*DIM + k0 + c*8);
        }
        __syncthreads();

        bf16x8 af[4][2], bfr[4][2];
        #pragma unroll
        for (int mi = 0; mi < 4; ++mi) {
            const u16* p = &as[(wm*64 + mi*16 + li)*LDG + quad*8];
            af[mi][0] = *(const bf16x8*)p;
            af[mi][1] = *(const bf16x8*)(p + 32);
        }
        #pragma unroll
        for (int ni = 0; ni < 4; ++ni) {
            const u16* p = &bs[(wn*64 + ni*16 + li)*LDG + quad*8];
            bfr[ni][0] = *(const bf16x8*)p;
            bfr[ni][1] = *(const bf16x8*)(p + 32);
        }
        #pragma unroll
        for (int mi = 0; mi < 4; ++mi)
            #pragma unroll
            for (int ni = 0; ni < 4; ++ni) {
                acc[mi][ni] = __builtin_amdgcn_mfma_f32_16x16x32_bf16(
                    af[mi][0], bfr[ni][0], acc[mi][ni], 0, 0, 0);
                acc[mi][ni] = __builtin_amdgcn_mfma_f32_16x16x32_bf16(
                    af[mi][1], bfr[ni][1], acc[mi][ni], 0, 0, 0);
            }
    }

    #pragma unroll
    for (int ni = 0; ni < 4; ++ni) {
        int col = n0 + wn*64 + ni*16 + li;
        float bias = bp[col];
        #pragma unroll
        for (int mi = 0; mi < 4; ++mi) {
            int r0 = row0 + wm*64 + mi*16 + quad*4;
            #pragma unroll
            for (int r = 0; r < 4; ++r)
                out[(size_t)(r0 + r)*DIM + col] = acc[mi][ni][r] + bias;
        }
    }
}

// ---------------- qsq: qsq[b,h,t] = sum_d q^2 ; asq[b,h] via 1 atomic/block
__global__ __launch_bounds__(256) void qsq_kernel(
    const u16* __restrict__ q16, float* __restrict__ qsq, float* __restrict__ asq)
{
    const int tid = threadIdx.x;
    const int bh = blockIdx.x >> 3;
    const int r0 = (blockIdx.x & 7) * 256;
    const u16* qb = q16 + ((size_t)bh * TT + r0) * HD;

    float tot = 0.0f;
    #pragma unroll
    for (int i = 0; i < 8; ++i) {
        int row = i * 32 + (tid >> 3);
        u16x8 v = *(const u16x8*)(qb + (size_t)row * HD + (tid & 7) * 8);
        float s = 0.0f;
        #pragma unroll
        for (int j = 0; j < 8; ++j) { float f = bf2f(v[j]); s += f * f; }
        tot += s;
        #pragma unroll
        for (int off = 1; off < 8; off <<= 1) s += __shfl_xor(s, off, 64);
        if ((tid & 7) == 0) qsq[(size_t)bh * TT + r0 + row] = s;
    }
    __shared__ float red[4];
    #pragma unroll
    for (int off = 32; off > 0; off >>= 1) tot += __shfl_down(tot, off, 64);
    if ((tid & 63) == 0) red[tid >> 6] = tot;
    __syncthreads();
    if (tid == 0) atomicAdd(&asq[bh], red[0] + red[1] + red[2] + red[3]);
}

// ---------------- attention v7: 32x32x16 MFMA (half the LDS frag bytes per
// FLOP), 8 waves = 4 row-groups x 2 intra-block s-halves, XOR-swizzled
// stride-64 staging (64 KB total), register shfl-transpose for P (no LDS
// P array), LDS end-combine + coalesced transpose write.
// 32x32 C/D layout (m74-verified): col = lane&31, row = (reg&3)+8*(reg>>2)+4*(lane>>5).
__global__ __launch_bounds__(512) void attn_kernel(
    const u16* __restrict__ q16, const u16* __restrict__ vt16,
    const float* __restrict__ qsq, const float* __restrict__ asq,
    const u32* __restrict__ bmaxsq, u16* __restrict__ ao16)
{
    const int tid = threadIdx.x;
    const int lane = tid & 63, w = tid >> 6;
    const int c = lane & 31, h = lane >> 5;
    const int rg = w & 3;          // row-group (32 q-rows)
    const int sh = w >> 2;         // s-half: 0 -> [0,1024), 1 -> [1024,2048)
    const int bh = blockIdx.x >> 4;
    const int qtile = blockIdx.x & 15;      // 16 tiles x 128 q-rows
    const int b = bh >> 3, hh = bh & 7;

    // [half][buf][row*64 + swizzled-chunk*8]; 64 KB total
    __shared__ __align__(16) u16 ks[2][2][64 * 64];
    __shared__ __align__(16) u16 vt[2][2][64 * 64];

    const u16* qg = q16  + (size_t)bh * TT * HD;    // [t][d]
    const u16* vg = vt16 + (size_t)bh * HD * TT;    // [d][t]
    const float* qsqg = qsq + (size_t)bh * TT;

    float cf;   // 100 * log2(e) / (a * bmax + eps)
    {
        float a  = sqrtf(asq[bh]);
        float bm = sqrtf(__uint_as_float(bmaxsq[b]));
        cf = (100.0f * 1.44269504089f) / (a * bm + 1e-10f);
    }
    const float c2 = 2.0f * cf;

    const int qt0w = qtile * 128 + rg * 32;
    // Q B-frags: B[k = kk*16 + h*8 + j][n = t = c], held in regs
    bf16x8 qf[4];
    #pragma unroll
    for (int kk = 0; kk < 4; ++kk)
        qf[kk] = *(const bf16x8*)(qg + (size_t)(qt0w + c) * HD + kk*16 + h*8);
    const float sqt = cf * qsqg[qt0w + c];

    // staging: 256 threads per half, 2 ks + 2 vt chunks each per tile
    const int lid = tid & 255;
    const int sc = lid & 7;
    const int r0s = lid >> 3;           // chunk rows r0s and r0s+32
    const int sbase = sh * 1024;
    const u16* kp0 = qg + (size_t)(sbase + r0s)      * HD + sc * 8;
    const u16* kp1 = qg + (size_t)(sbase + r0s + 32) * HD + sc * 8;
    const u16* vp0 = vg + (size_t)r0s        * TT + sbase + sc * 8;
    const u16* vp1 = vg + (size_t)(r0s + 32) * TT + sbase + sc * 8;
    const int so0 = r0s * 64        + ((sc ^ (r0s & 7)) * 8);
    const int so1 = (r0s + 32) * 64 + ((sc ^ ((r0s + 32) & 7)) * 8);

    u16* ksb[2] = { &ks[sh][0][0], &ks[sh][1][0] };
    u16* vtb[2] = { &vt[sh][0][0], &vt[sh][1][0] };

    float ssum = 0.0f;
    f32x16 o[2];
    #pragma unroll
    for (int dB = 0; dB < 2; ++dB)
        #pragma unroll
        for (int r = 0; r < 16; ++r) o[dB][r] = 0.0f;

    const int cx = c & 7;   // swizzle term for frag reads (rows +32 share &7)

    auto tile_compute = [&](const u16* __restrict__ kt,
                            const u16* __restrict__ vv, int s0) {
        u32 pq[2][8];
        // ---- S^T = K Q^T per 32-s block
        #pragma unroll
        for (int sB = 0; sB < 2; ++sB) {
            f32x16 acc;
            #pragma unroll
            for (int r = 0; r < 16; ++r) acc[r] = 0.0f;
            #pragma unroll
            for (int kk = 0; kk < 4; ++kk) {
                bf16x8 kf = *(const bf16x8*)(kt + (sB*32 + c)*64
                                             + (((2*kk + h) ^ cx) * 8));
                acc = __builtin_amdgcn_mfma_f32_32x32x16_bf16(kf, qf[kk], acc, 0, 0, 0);
            }
            #pragma unroll
            for (int g = 0; g < 4; ++g) {
                f32x4 q4 = *(const f32x4*)(qsqg + s0 + sB*32 + 8*g + 4*h);
                float t0 = fmaf(cf, q4[0], sqt);
                float t1 = fmaf(cf, q4[1], sqt);
                float t2 = fmaf(cf, q4[2], sqt);
                float t3 = fmaf(cf, q4[3], sqt);
                float p0 = __builtin_amdgcn_exp2f(fmaf(c2, acc[4*g+0], -t0));
                float p1 = __builtin_amdgcn_exp2f(fmaf(c2, acc[4*g+1], -t1));
                float p2 = __builtin_amdgcn_exp2f(fmaf(c2, acc[4*g+2], -t2));
                float p3 = __builtin_amdgcn_exp2f(fmaf(c2, acc[4*g+3], -t3));
                ssum += (p0 + p1) + (p2 + p3);
                pq[sB][2*g]   = cvtpk(p0, p1);
                pq[sB][2*g+1] = cvtpk(p2, p3);
            }
        }
        // ---- PV: B-frags assembled in regs via shfl_xor(32)
        #pragma unroll
        for (int kk = 0; kk < 4; ++kk) {
            const int sB = kk >> 1;
            const int e = (kk & 1) * 2;
            u32 own0 = h ? pq[sB][2*(e+1)]   : pq[sB][2*e];
            u32 own1 = h ? pq[sB][2*(e+1)+1] : pq[sB][2*e+1];
            u32 pub0 = h ? pq[sB][2*e]       : pq[sB][2*(e+1)];
            u32 pub1 = h ? pq[sB][2*e+1]     : pq[sB][2*(e+1)+1];
            u32 rx0 = (u32)__shfl_xor((int)pub0, 32, 64);
            u32 rx1 = (u32)__shfl_xor((int)pub1, 32, 64);
            u32 m0 = h ? rx0 : own0;
            u32 m1 = h ? rx1 : own1;
            u32 m2 = h ? own0 : rx0;
            u32 m3 = h ? own1 : rx1;
            union { u32 u[4]; bf16x8 v; } bfr;
            bfr.u[0] = m0; bfr.u[1] = m1; bfr.u[2] = m2; bfr.u[3] = m3;
            #pragma unroll
            for (int dB = 0; dB < 2; ++dB) {
                bf16x8 vf = *(const bf16x8*)(vv + (dB*32 + c)*64
                                             + (((2*kk + h) ^ cx) * 8));
                o[dB] = __builtin_amdgcn_mfma_f32_32x32x16_bf16(vf, bfr.v, o[dB], 0, 0, 0);
            }
        }
    };

    // preload tile 0 into buf0
    bf16x8 k0r = *(const bf16x8*)kp0, k1r = *(const bf16x8*)kp1;
    bf16x8 v0r = *(const bf16x8*)vp0, v1r = *(const bf16x8*)vp1;
    *(bf16x8*)(ksb[0] + so0) = k0r;  *(bf16x8*)(ksb[0] + so1) = k1r;
    *(bf16x8*)(vtb[0] + so0) = v0r;  *(bf16x8*)(vtb[0] + so1) = v1r;
    __syncthreads();

    for (int t2 = 0; t2 < 8; ++t2) {
        const int tl = 2 * t2;
        k0r = *(const bf16x8*)(kp0 + (size_t)(tl+1)*64*HD);
        k1r = *(const bf16x8*)(kp1 + (size_t)(tl+1)*64*HD);
        v0r = *(const bf16x8*)(vp0 + (tl+1)*64);
        v1r = *(const bf16x8*)(vp1 + (tl+1)*64);
        tile_compute(ksb[0], vtb[0], sbase + tl*64);
        *(bf16x8*)(ksb[1] + so0) = k0r;  *(bf16x8*)(ksb[1] + so1) = k1r;
        *(bf16x8*)(vtb[1] + so0) = v0r;  *(bf16x8*)(vtb[1] + so1) = v1r;
        __syncthreads();
        if (t2 < 7) {
            k0r = *(const bf16x8*)(kp0 + (size_t)(tl+2)*64*HD);
            k1r = *(const bf16x8*)(kp1 + (size_t)(tl+2)*64*HD);
            v0r = *(const bf16x8*)(vp0 + (tl+2)*64);
            v1r = *(const bf16x8*)(vp1 + (tl+2)*64);
        }
        tile_compute(ksb[1], vtb[1], sbase + (tl+1)*64);
        if (t2 < 7) {
            *(bf16x8*)(ksb[0] + so0) = k0r;  *(bf16x8*)(ksb[0] + so1) = k1r;
            *(bf16x8*)(vtb[0] + so0) = v0r;  *(bf16x8*)(vtb[0] + so1) = v1r;
        }
        __syncthreads();
    }

    // per-lane half-denominator for t = qt0w + c
    ssum += __shfl_xor(ssum, 32, 64);

    // ---- combine the two s-halves through (now-dead) staging LDS
    float* sc_o = (float*)&ks[0][0][0];               // 32 KB
    float* sc_s = (float*)&vt[0][0][0];               // 1 KB
    u16*   sc_a = (u16*)(sc_s + 512);                 // 16 KB ao staging

    if (sh == 1) {
        #pragma unroll
        for (int dB = 0; dB < 2; ++dB)
            #pragma unroll
            for (int r = 0; r < 16; ++r)
                sc_o[(((rg*2 + dB)*16 + r)*64) + h*32 + c] = o[dB][r];
        sc_s[rg*64 + h*32 + c] = ssum;
    }
    __syncthreads();
    if (sh == 0) {
        float inv = 1.0f / (ssum + sc_s[rg*64 + h*32 + c]);
        #pragma unroll
        for (int dB = 0; dB < 2; ++dB)
            #pragma unroll
            for (int g = 0; g < 4; ++g) {
                float v0 = (o[dB][4*g+0] + sc_o[(((rg*2+dB)*16 + 4*g+0)*64) + h*32 + c]) * inv;
                float v1 = (o[dB][4*g+1] + sc_o[(((rg*2+dB)*16 + 4*g+1)*64) + h*32 + c]) * inv;
                float v2 = (o[dB][4*g+2] + sc_o[(((rg*2+dB)*16 + 4*g+2)*64) + h*32 + c]) * inv;
                float v3 = (o[dB][4*g+3] + sc_o[(((rg*2+dB)*16 + 4*g+3)*64) + h*32 + c]) * inv;
                int d = dB*32 + 8*g + 4*h;            // rows d..d+3
                u32* dst = (u32*)&sc_a[(rg*32 + c)*64 + d];
                dst[0] = cvtpk(v0, v1);
                dst[1] = cvtpk(v2, v3);
            }
    }
    __syncthreads();
    // coalesced transpose write: 128 t-rows x 64 d (128 B each)
    #pragma unroll
    for (int i = 0; i < 2; ++i) {
        int id = i*512 + tid;
        int row = id >> 3, col = (id & 7) * 8;
        u16x8 vv = *(const u16x8*)&sc_a[row*64 + col];
        *(u16x8*)(ao16 + ((size_t)(b*TT + qtile*128 + row))*DIM + hh*HD + col) = vv;
    }
}

extern "C" void kernel_launch(void* const* d_in, const int* in_sizes, int n_in,
                              void* d_out, int out_size, void* d_ws, size_t ws_size,
                              hipStream_t stream)
{
    const float* x     = (const float*)d_in[0];   // [4,2048,512] f32
    const float* Wqkv  = (const float*)d_in[1];   // [512,1024]  f32
    const float* Wproj = (const float*)d_in[2];   // [512,512]   f32
    const float* bproj = (const float*)d_in[3];   // [512]       f32
    float* out = (float*)d_out;                   // [4,2048,512] f32

    char* ws = (char*)d_ws;
    const size_t MB = 1024*1024;
    u16*   q16  = (u16*)(ws);                          // 8 MB  [b,h,t,d] bf16
    u16*   vt16 = (u16*)(ws + 8*MB);                   // 8 MB  [b,h,d,t] bf16
    u16*   ao16 = (u16*)(ws + 16*MB);                  // 8 MB  [b,t,dim] bf16
    u16*   x16  = (u16*)(ws + 24*MB);                  // 8 MB  [b,t,dim] bf16
    u16*   Wtq  = (u16*)(ws + 32*MB);                  // 1 MB  [1024][512]
    u16*   Wtp  = (u16*)(ws + 33*MB);                  // 0.5MB [512][512]
    float* qsq  = (float*)(ws + 34*MB);                // 256 KB (16B aligned)
    float* asq  = (float*)(ws + 34*MB + 262144);       // 128 B
    u32* bmaxsq = (u32*)(ws + 34*MB + 262144 + 128);   // 16 B

    (void)in_sizes; (void)n_in; (void)out_size; (void)ws_size;

    hipMemsetAsync(ws + 34*MB + 262144, 0, 144, stream);

    prep_kernel<<<1024, 256, 0, stream>>>(x, x16, bmaxsq, Wqkv, Wtq, Wproj, Wtp);

    qkv_mfma<<<64*8, 256, 0, stream>>>(x16, Wtq, q16, vt16);

    qsq_kernel<<<BH*8, 256, 0, stream>>>(q16, qsq, asq);

    attn_kernel<<<BH*16, 512, 0, stream>>>(q16, vt16, qsq, asq, bmaxsq, ao16);

    proj_mfma<<<64*4, 256, 0, stream>>>(ao16, Wtp, bproj, out);
}